// Round 1
// baseline (3167.841 us; speedup 1.0000x reference)
//
#include <hip/hip_runtime.h>
#include <hip/hip_bf16.h>
#include <cstdint>
#include <cstddef>

#define T0_ 512
#define T1_ 1536
#define TT_ 2048
#define WD_ 2048
#define NH_ 16
#define KH_ 4
#define HD_ 128

// ---------------------------------------------------------------------------
// Generic tiled f32 GEMM:  C[t, z, c] = sum_d A[t, d] * W[z, d, c]
//   A: (M, 2048) row-major, lda = 2048
//   W: (mats, 2048, cols) row-major slabs
//   C: row t stride = ldc, slab offset z*cols
// grid = (cols/64, M/64, mats), block = 256
// ---------------------------------------------------------------------------
__global__ __launch_bounds__(256) void gemm_f32(
    const float* __restrict__ A, const float* __restrict__ W,
    float* __restrict__ C, int cols, int ldc)
{
  __shared__ float As[16][65];
  __shared__ float Bs[16][68];
  const int z = blockIdx.z;
  const float* B = W + (size_t)z * WD_ * cols;
  float* Cz = C + (size_t)z * cols;
  const int row0 = blockIdx.y * 64;
  const int col0 = blockIdx.x * 64;
  const int t  = threadIdx.x;
  const int ty = t >> 4, tx = t & 15;
  const int ar = t >> 2, ac = (t & 3) * 4;   // A loader: row ar, 4 floats at ac
  const int br = t >> 4, bc = (t & 15) * 4;  // B loader: row br, 4 floats at bc
  const float* Aptr = A + (size_t)(row0 + ar) * WD_ + ac;
  const float* Bptr = B + (size_t)br * cols + (col0 + bc);

  float acc[4][4] = {};
  for (int k0 = 0; k0 < WD_; k0 += 16) {
    const float4 av = *(const float4*)(Aptr + k0);
    const float4 bv = *(const float4*)(Bptr + (size_t)k0 * cols);
    __syncthreads();
    As[ac + 0][ar] = av.x; As[ac + 1][ar] = av.y;
    As[ac + 2][ar] = av.z; As[ac + 3][ar] = av.w;
    *(float4*)&Bs[br][bc] = bv;
    __syncthreads();
#pragma unroll
    for (int kk = 0; kk < 16; ++kk) {
      float a[4], b[4];
#pragma unroll
      for (int i = 0; i < 4; ++i) a[i] = As[kk][ty + 16 * i];
#pragma unroll
      for (int j = 0; j < 4; ++j) b[j] = Bs[kk][tx + 16 * j];
#pragma unroll
      for (int i = 0; i < 4; ++i)
#pragma unroll
        for (int j = 0; j < 4; ++j) acc[i][j] += a[i] * b[j];
    }
  }
#pragma unroll
  for (int i = 0; i < 4; ++i) {
    const int r = row0 + ty + 16 * i;
#pragma unroll
    for (int j = 0; j < 4; ++j)
      Cz[(size_t)r * ldc + (col0 + tx + 16 * j)] = acc[i][j];
  }
}

// ---------------------------------------------------------------------------
// RMSNorm + RoPE (+ q scale) applied row-wise, in place.
//   qg: (T, N, 256)   cols 0..127 = q (transformed in place), 128..255 = gate
//   kc: (T, K, 128)   raw k proj -> normed+roped (this IS cached_k)
// grid = (T), block = 256 (4 waves; each wave handles whole rows)
// ---------------------------------------------------------------------------
__global__ __launch_bounds__(256) void postproc(
    float* __restrict__ qg, float* __restrict__ kc,
    const int* __restrict__ positions,
    const float* __restrict__ qn0, const float* __restrict__ kn0,
    const float* __restrict__ qn1, const float* __restrict__ kn1)
{
  const int t = blockIdx.x;
  const int w = threadIdx.x >> 6;
  const int l = threadIdx.x & 63;
  const float pos = (float)positions[t];
  const bool s1 = (t >= T0_);
  const float* qn = s1 ? qn1 : qn0;
  const float* kn = s1 ? kn1 : kn0;
  const float kfreq = 13.815510557964274f / 32.0f;  // ln(1e6)/half

  for (int r = w; r < NH_ + KH_; r += 4) {
    float* row;
    const float* sc;
    const bool isq = (r < NH_);
    if (isq) { row = qg + ((size_t)t * NH_ + r) * 256; sc = qn; }
    else     { row = kc + ((size_t)t * KH_ + (r - NH_)) * 128; sc = kn; }
    const int h0 = 2 * l, h1 = 2 * l + 1;
    float v0 = row[h0], v1 = row[h1];
    float ss = v0 * v0 + v1 * v1;
#pragma unroll
    for (int off = 32; off > 0; off >>= 1) ss += __shfl_xor(ss, off);
    const float rstd = rsqrtf(ss * (1.0f / 128.0f) + 1e-6f);
    v0 = v0 * rstd * (1.0f + sc[h0]);
    v1 = v1 * rstd * (1.0f + sc[h1]);
    // RoPE over h in [0,64): x1 = h in [0,32), x2 = h in [32,64)
    const float p0 = __shfl_xor(v0, 16);
    const float p1 = __shfl_xor(v1, 16);
    if (l < 32) {
      const int i0 = (l < 16) ? h0 : (h0 - 32);
      const float a0 = pos * __expf(-(float)i0 * kfreq);
      const float a1 = pos * __expf(-(float)(i0 + 1) * kfreq);
      const float c0 = cosf(a0), s0 = sinf(a0);
      const float c1 = cosf(a1), s1v = sinf(a1);
      if (l < 16) { v0 = v0 * c0 - p0 * s0;  v1 = v1 * c1 - p1 * s1v; }
      else        { v0 = v0 * c0 + p0 * s0;  v1 = v1 * c1 + p1 * s1v; }
    }
    if (isq) { v0 *= 0.08838834764831843f; v1 *= 0.08838834764831843f; }
    row[h0] = v0; row[h1] = v1;
  }
}

// ---------------------------------------------------------------------------
// Flash-style causal attention + sigmoid-gate fusion.
//   qg:  (T, N, 256)  q (scaled, roped) in [0:128], raw gate in [128:256]
//   kc:  (T, K, 128)  roped k        vc: (T, K, 128)
//   enc: (T, N, 128)  output (already gated)
// grid = (T/32, N), block = 256
// ---------------------------------------------------------------------------
__global__ __launch_bounds__(256) void attn(
    const float* __restrict__ qg, const float* __restrict__ kc,
    const float* __restrict__ vc, float* __restrict__ enc)
{
  __shared__ float Qs[32 * 132];
  __shared__ float Ks[32 * 132];
  __shared__ float Vs[32 * 132];
  __shared__ float Ss[32 * 33];
  __shared__ float mrow[32], lrow[32], arow[32];

  const int tid = threadIdx.x;
  const int qt = blockIdx.x, n = blockIdx.y;
  const int kn = n >> 2;           // N/K = 4
  const int rw = tid >> 3;         // 0..31 (load & PV row)
  const int cc = tid & 7;          // 0..7  (16-float column group)

  {  // stage Q tile
    const float* qb = qg + ((size_t)(qt * 32 + rw) * NH_ + n) * 256;
#pragma unroll
    for (int j = 0; j < 4; ++j)
      *(float4*)&Qs[rw * 132 + cc * 16 + 4 * j] = *(const float4*)(qb + cc * 16 + 4 * j);
  }
  if (tid < 32) { mrow[tid] = -3.0e38f; lrow[tid] = 0.0f; }
  float acc[16];
#pragma unroll
  for (int i = 0; i < 16; ++i) acc[i] = 0.0f;

  const int jj = tid & 31, ib = tid >> 5;  // S-phase mapping

  for (int st = 0; st <= qt; ++st) {
    __syncthreads();  // prior tile fully consumed
    {  // stage K/V tile
      const float* kb = kc + ((size_t)(st * 32 + rw) * KH_ + kn) * 128;
      const float* vb = vc + ((size_t)(st * 32 + rw) * KH_ + kn) * 128;
#pragma unroll
      for (int j = 0; j < 4; ++j) {
        *(float4*)&Ks[rw * 132 + cc * 16 + 4 * j] = *(const float4*)(kb + cc * 16 + 4 * j);
        *(float4*)&Vs[rw * 132 + cc * 16 + 4 * j] = *(const float4*)(vb + cc * 16 + 4 * j);
      }
    }
    __syncthreads();

    // S = Q K^T : thread computes rows {ib, ib+8, ib+16, ib+24}, col jj
    float s[4] = {0.f, 0.f, 0.f, 0.f};
    for (int g = 0; g < 32; ++g) {
      const float4 kv = *(const float4*)&Ks[jj * 132 + 4 * g];
#pragma unroll
      for (int r = 0; r < 4; ++r) {
        const float4 qv = *(const float4*)&Qs[(ib + 8 * r) * 132 + 4 * g];
        s[r] += qv.x * kv.x + qv.y * kv.y + qv.z * kv.z + qv.w * kv.w;
      }
    }
#pragma unroll
    for (int r = 0; r < 4; ++r) Ss[(ib + 8 * r) * 33 + jj] = s[r];
    __syncthreads();

    // online softmax row update
    if (tid < 32) {
      const int i = tid;
      const int jmax = (st == qt) ? i : 31;  // causal
      const float m = mrow[i];
      float mn = m;
      for (int j = 0; j <= jmax; ++j) mn = fmaxf(mn, Ss[i * 33 + j]);
      const float alpha = __expf(m - mn);
      float sum = 0.f;
      for (int j = 0; j < 32; ++j) {
        const float p = (j <= jmax) ? __expf(Ss[i * 33 + j] - mn) : 0.0f;
        Ss[i * 33 + j] = p;
        sum += p;
      }
      lrow[i] = lrow[i] * alpha + sum;
      mrow[i] = mn;
      arow[i] = alpha;
    }
    __syncthreads();

    // O += P V  (thread: row rw, h = cc*16 + 0..15)
    const float alpha = arow[rw];
#pragma unroll
    for (int h = 0; h < 16; ++h) acc[h] *= alpha;
    for (int j = 0; j < 32; ++j) {
      const float p = Ss[rw * 33 + j];
      const float* vr = &Vs[j * 132 + cc * 16];
#pragma unroll
      for (int g = 0; g < 4; ++g) {
        const float4 vv = *(const float4*)(vr + 4 * g);
        acc[4 * g + 0] += p * vv.x; acc[4 * g + 1] += p * vv.y;
        acc[4 * g + 2] += p * vv.z; acc[4 * g + 3] += p * vv.w;
      }
    }
  }

  // epilogue: 1/l, sigmoid gate, store
  const float linv = 1.0f / lrow[rw];
  const size_t tg = (size_t)(qt * 32 + rw);
  const float* gb = qg + (tg * NH_ + n) * 256 + 128 + cc * 16;
  float* ob = enc + (tg * NH_ + n) * 128 + cc * 16;
#pragma unroll
  for (int g = 0; g < 4; ++g) {
    float4 o;
    o.x = acc[4 * g + 0] * linv * (1.0f / (1.0f + __expf(-gb[4 * g + 0])));
    o.y = acc[4 * g + 1] * linv * (1.0f / (1.0f + __expf(-gb[4 * g + 1])));
    o.z = acc[4 * g + 2] * linv * (1.0f / (1.0f + __expf(-gb[4 * g + 2])));
    o.w = acc[4 * g + 3] * linv * (1.0f / (1.0f + __expf(-gb[4 * g + 3])));
    *(float4*)(ob + 4 * g) = o;
  }
}

// ---------------------------------------------------------------------------
extern "C" void kernel_launch(void* const* d_in, const int* in_sizes, int n_in,
                              void* d_out, int out_size, void* d_ws, size_t ws_size,
                              hipStream_t stream)
{
  (void)in_sizes; (void)n_in; (void)out_size; (void)ws_size;
  const float* x0    = (const float*)d_in[0];
  const float* x1    = (const float*)d_in[1];
  const int*   pos   = (const int*)d_in[2];
  // d_in[3] attn_mask: known causal tril -> unused
  const float* qg_w0 = (const float*)d_in[4];
  const float* k_w0  = (const float*)d_in[5];
  const float* v_w0  = (const float*)d_in[6];
  const float* qn0   = (const float*)d_in[7];
  const float* kn0   = (const float*)d_in[8];
  const float* o_w0  = (const float*)d_in[9];
  const float* qg_w1 = (const float*)d_in[10];
  const float* k_w1  = (const float*)d_in[11];
  const float* v_w1  = (const float*)d_in[12];
  const float* qn1   = (const float*)d_in[13];
  const float* kn1   = (const float*)d_in[14];
  const float* o_w1  = (const float*)d_in[15];

  float* out    = (float*)d_out;
  float* out0   = out;                                   // (512, 2048)
  float* out1   = out + (size_t)T0_ * WD_;               // (1536, 2048)
  float* kcache = out + (size_t)TT_ * WD_;               // (2048, 4, 128)
  float* vcache = kcache + (size_t)TT_ * KH_ * HD_;      // (2048, 4, 128)

  float* ws  = (float*)d_ws;
  float* qgb = ws;                                       // (2048, 16, 256) = 33.5 MB
  float* enc = ws + (size_t)TT_ * NH_ * 256;             // (2048, 16, 128) = 16.8 MB

  const dim3 blk(256);

  // --- projections (raw) ---
  // qg: (T, N, 2H), ldc = N*2H = 4096
  gemm_f32<<<dim3(4, T0_ / 64, NH_), blk, 0, stream>>>(x0, qg_w0, qgb, 256, 4096);
  gemm_f32<<<dim3(4, T1_ / 64, NH_), blk, 0, stream>>>(x1, qg_w1, qgb + (size_t)T0_ * 4096, 256, 4096);
  // k -> cached_k region (raw, normed+roped in place afterwards), ldc = K*H = 512
  gemm_f32<<<dim3(2, T0_ / 64, KH_), blk, 0, stream>>>(x0, k_w0, kcache, 128, 512);
  gemm_f32<<<dim3(2, T1_ / 64, KH_), blk, 0, stream>>>(x1, k_w1, kcache + (size_t)T0_ * 512, 128, 512);
  // v -> cached_v region (final, no post-processing)
  gemm_f32<<<dim3(2, T0_ / 64, KH_), blk, 0, stream>>>(x0, v_w0, vcache, 128, 512);
  gemm_f32<<<dim3(2, T1_ / 64, KH_), blk, 0, stream>>>(x1, v_w1, vcache + (size_t)T0_ * 512, 128, 512);

  // --- RMSNorm + RoPE (+ q scale) in place ---
  postproc<<<dim3(TT_), blk, 0, stream>>>(qgb, kcache, pos, qn0, kn0, qn1, kn1);

  // --- attention (causal, online softmax, gate fused) ---
  attn<<<dim3(TT_ / 32, NH_), blk, 0, stream>>>(qgb, kcache, vcache, enc);

  // --- output projections ---
  gemm_f32<<<dim3(32, T0_ / 64, 1), blk, 0, stream>>>(enc, o_w0, out0, 2048, 2048);
  gemm_f32<<<dim3(32, T1_ / 64, 1), blk, 0, stream>>>(enc + (size_t)T0_ * 2048, o_w1, out1, 2048, 2048);
}

// Round 2
// 715.418 us; speedup vs baseline: 4.4280x; 4.4280x over previous
//
#include <hip/hip_runtime.h>
#include <hip/hip_bf16.h>
#include <cstdint>
#include <cstddef>

#define T0_ 512
#define TT_ 2048
#define WD_ 2048
#define NH_ 16
#define KH_ 4

typedef __attribute__((ext_vector_type(8))) short short8;
typedef __attribute__((ext_vector_type(4))) float f32x4;

#define AS1 __attribute__((address_space(1)))
#define AS3 __attribute__((address_space(3)))

__device__ __forceinline__ ushort f2bf(float x) {
  __hip_bfloat16 h = __float2bfloat16(x);
  ushort u; __builtin_memcpy(&u, &h, 2); return u;
}
__device__ __forceinline__ float bf2f(ushort u) {
  __hip_bfloat16 h; __builtin_memcpy(&h, &u, 2);
  return __bfloat162float(h);
}
__device__ __forceinline__ void g2l16(const ushort* g, AS3 ushort* s) {
  __builtin_amdgcn_global_load_lds((const AS1 uint32_t*)g, (AS3 uint32_t*)s, 16, 0, 0);
}

// ---------------------------------------------------------------------------
// x0/x1 (f32) -> xb (2048x2048 bf16)
__global__ __launch_bounds__(256) void convert_x(
    const float* __restrict__ x0, const float* __restrict__ x1, ushort* __restrict__ xb)
{
  const int i = blockIdx.x * 256 + threadIdx.x;
  const int e = i * 4;
  const int row = e >> 11, col = e & 2047;
  const float* src = (row < T0_) ? (x0 + (size_t)row * WD_ + col)
                                 : (x1 + (size_t)(row - T0_) * WD_ + col);
  const float4 v = *(const float4*)src;
  ushort4 o; o.x = f2bf(v.x); o.y = f2bf(v.y); o.z = f2bf(v.z); o.w = f2bf(v.w);
  *(ushort4*)(xb + e) = o;
}

// ---------------------------------------------------------------------------
// Transpose-convert: in f32 (slab, R, C) -> out bf16 (slab, C, R)
// grid (R/32, C/32, slabs), block 256
__global__ __launch_bounds__(256) void convtrans(
    const float* __restrict__ in, ushort* __restrict__ out, int R, int C)
{
  __shared__ float tile[32][33];
  const int z = blockIdx.z;
  in  += (size_t)z * R * C;
  out += (size_t)z * R * C;
  const int r0 = blockIdx.x * 32, c0 = blockIdx.y * 32;
  const int tx = threadIdx.x & 31, ty = threadIdx.x >> 5;
#pragma unroll
  for (int i = 0; i < 4; ++i)
    tile[ty + 8 * i][tx] = in[(size_t)(r0 + ty + 8 * i) * C + c0 + tx];
  __syncthreads();
#pragma unroll
  for (int i = 0; i < 4; ++i)
    out[(size_t)(c0 + ty + 8 * i) * R + r0 + tx] = f2bf(tile[tx][ty + 8 * i]);
}

// ---------------------------------------------------------------------------
// bf16 MFMA GEMM (m97 structure): C(MxN) = A(Mx2048) * Bt(Nx2048)^T
// A, Bt row-major k-contiguous bf16. 128x128 tile, BK=32, 256 thr (4 waves 2x2).
// Writes f32 C (if Cf) and/or bf16 C (if Cb), plain row-major ldc.
__global__ __launch_bounds__(256) void gemm_bf16(
    const ushort* __restrict__ A, const ushort* __restrict__ Bt,
    float* __restrict__ Cf, ushort* __restrict__ Cb, int ldc)
{
  __shared__ ushort As[128 * 32];
  __shared__ ushort Bs[128 * 32];
  const int tid = threadIdx.x;
  const int w = tid >> 6, l = tid & 63, lq = l >> 4, lm = l & 15;
  const int row0 = blockIdx.y * 128, col0 = blockIdx.x * 128;
  const int wr = (w >> 1) * 64, wc = (w & 1) * 64;
  const ushort* Ag = A + (size_t)(row0 + (tid >> 2)) * WD_ + (tid & 3) * 8;
  const ushort* Bg = Bt + (size_t)(col0 + (tid >> 2)) * WD_ + (tid & 3) * 8;
  AS3 ushort* AsW = (AS3 ushort*)As + w * 512;
  AS3 ushort* BsW = (AS3 ushort*)Bs + w * 512;
  f32x4 acc[4][4];
#pragma unroll
  for (int mi = 0; mi < 4; ++mi)
#pragma unroll
    for (int ni = 0; ni < 4; ++ni) acc[mi][ni] = (f32x4){0.f, 0.f, 0.f, 0.f};

  for (int k0 = 0; k0 < WD_; k0 += 32) {
    __syncthreads();
    g2l16(Ag + k0, AsW);
    g2l16(Ag + (size_t)64 * WD_ + k0, AsW + 2048);
    g2l16(Bg + k0, BsW);
    g2l16(Bg + (size_t)64 * WD_ + k0, BsW + 2048);
    __syncthreads();
    short8 af[4], bfr[4];
#pragma unroll
    for (int mi = 0; mi < 4; ++mi)
      af[mi] = *(const short8*)&As[(wr + mi * 16 + lm) * 32 + lq * 8];
#pragma unroll
    for (int ni = 0; ni < 4; ++ni)
      bfr[ni] = *(const short8*)&Bs[(wc + ni * 16 + lm) * 32 + lq * 8];
#pragma unroll
    for (int mi = 0; mi < 4; ++mi)
#pragma unroll
      for (int ni = 0; ni < 4; ++ni)
        acc[mi][ni] = __builtin_amdgcn_mfma_f32_16x16x32_bf16(af[mi], bfr[ni], acc[mi][ni], 0, 0, 0);
  }
#pragma unroll
  for (int mi = 0; mi < 4; ++mi)
#pragma unroll
    for (int ni = 0; ni < 4; ++ni)
#pragma unroll
      for (int r = 0; r < 4; ++r) {
        const size_t rr = (size_t)row0 + wr + mi * 16 + lq * 4 + r;
        const size_t cc = (size_t)col0 + wc + ni * 16 + lm;
        const float v = acc[mi][ni][r];
        if (Cf) Cf[rr * ldc + cc] = v;
        if (Cb) Cb[rr * ldc + cc] = f2bf(v);
      }
}

// ---------------------------------------------------------------------------
// RMSNorm + RoPE (+ q scale). qgb bf16 (t,n,256) q in-place; kcache f32
// in-place (this IS cached_k) + bf16 copy Kb (t,kh,128).
__global__ __launch_bounds__(256) void postproc(
    ushort* __restrict__ qgb, float* __restrict__ kc, ushort* __restrict__ Kb,
    const int* __restrict__ positions,
    const float* __restrict__ qn0, const float* __restrict__ kn0,
    const float* __restrict__ qn1, const float* __restrict__ kn1)
{
  const int t = blockIdx.x;
  const int w = threadIdx.x >> 6, l = threadIdx.x & 63;
  const float pos = (float)positions[t];
  const bool str1 = (t >= T0_);
  const float* qn = str1 ? qn1 : qn0;
  const float* kn = str1 ? kn1 : kn0;
  const float kfreq = 13.815510557964274f / 32.0f;  // ln(1e6)/32
  const int h0 = 2 * l, h1 = 2 * l + 1;

  for (int r = w; r < NH_ + KH_; r += 4) {
    const bool isq = (r < NH_);
    float v0, v1; size_t bi; const float* sc;
    if (isq) {
      bi = ((size_t)t * NH_ + r) * 256;
      v0 = bf2f(qgb[bi + h0]); v1 = bf2f(qgb[bi + h1]); sc = qn;
    } else {
      bi = ((size_t)t * KH_ + (r - NH_)) * 128;
      v0 = kc[bi + h0]; v1 = kc[bi + h1]; sc = kn;
    }
    float ss = v0 * v0 + v1 * v1;
#pragma unroll
    for (int off = 32; off > 0; off >>= 1) ss += __shfl_xor(ss, off);
    const float rstd = rsqrtf(ss * (1.0f / 128.0f) + 1e-6f);
    v0 = v0 * rstd * (1.0f + sc[h0]);
    v1 = v1 * rstd * (1.0f + sc[h1]);
    const float p0 = __shfl_xor(v0, 16);
    const float p1 = __shfl_xor(v1, 16);
    if (l < 32) {
      const int i0 = (l < 16) ? h0 : (h0 - 32);
      const float a0 = pos * __expf(-(float)i0 * kfreq);
      const float a1 = pos * __expf(-(float)(i0 + 1) * kfreq);
      const float c0 = cosf(a0), s0 = sinf(a0);
      const float c1 = cosf(a1), s1v = sinf(a1);
      if (l < 16) { v0 = v0 * c0 - p0 * s0; v1 = v1 * c1 - p1 * s1v; }
      else        { v0 = v0 * c0 + p0 * s0; v1 = v1 * c1 + p1 * s1v; }
    }
    if (isq) {
      v0 *= 0.08838834764831843f; v1 *= 0.08838834764831843f;
      qgb[bi + h0] = f2bf(v0); qgb[bi + h1] = f2bf(v1);
    } else {
      kc[bi + h0] = v0; kc[bi + h1] = v1;
      Kb[bi + h0] = f2bf(v0); Kb[bi + h1] = f2bf(v1);
    }
  }
}

// ---------------------------------------------------------------------------
// Flash attention, MFMA. 64-row Q tile per block, 64-col K/V tiles.
// qgb: normed q bf16 + raw gate bf16 (t,n,256); Kb (t,kh,128); Vt (kh,128,2048).
// encb out bf16 (t, n*128+h).
__global__ __launch_bounds__(256) void attn(
    const ushort* __restrict__ qgb, const ushort* __restrict__ Kb,
    const ushort* __restrict__ Vt, ushort* __restrict__ encb)
{
  __shared__ ushort Ks[64 * 128];   // [s][h]
  __shared__ ushort Vs[128 * 64];   // [h][s]
  __shared__ ushort Ps[4 * 16 * 80];// per-wave 16x64, rowstride 80
  const int tid = threadIdx.x;
  const int w = tid >> 6, l = tid & 63, lq = l >> 4, lm = l & 15;
  const int qt = (int)gridDim.x - 1 - (int)blockIdx.x;  // heavy blocks first
  const int n = blockIdx.y, kh = n >> 2;

  short8 aq[4];
  {
    const ushort* qb = qgb + ((size_t)(qt * 64 + w * 16 + lm) * NH_ + n) * 256 + lq * 8;
#pragma unroll
    for (int kk = 0; kk < 4; ++kk) aq[kk] = *(const short8*)(qb + kk * 32);
  }
  f32x4 acc[8];
#pragma unroll
  for (int i = 0; i < 8; ++i) acc[i] = (f32x4){0.f, 0.f, 0.f, 0.f};
  float m4[4] = {-3.0e38f, -3.0e38f, -3.0e38f, -3.0e38f};
  float l4[4] = {0.f, 0.f, 0.f, 0.f};

  AS3 ushort* KsW = (AS3 ushort*)Ks + w * 512;
  AS3 ushort* VsW = (AS3 ushort*)Vs + w * 512;
  const ushort* Kg = Kb + ((size_t)(tid >> 4) * KH_ + kh) * 128 + (tid & 15) * 8;
  const ushort* Vg = Vt + ((size_t)kh * 128 + (tid >> 3)) * TT_ + (tid & 7) * 8;

  for (int st = 0; st <= qt; ++st) {
    const int s0 = st * 64;
    __syncthreads();
#pragma unroll
    for (int c = 0; c < 4; ++c) {
      g2l16(Kg + (size_t)(s0 + 16 * c) * (KH_ * 128), KsW + c * 2048);
      g2l16(Vg + (size_t)(32 * c) * TT_ + s0, VsW + c * 2048);
    }
    __syncthreads();

    f32x4 sa[4];
#pragma unroll
    for (int ni = 0; ni < 4; ++ni) sa[ni] = (f32x4){0.f, 0.f, 0.f, 0.f};
#pragma unroll
    for (int kk = 0; kk < 4; ++kk)
#pragma unroll
      for (int ni = 0; ni < 4; ++ni) {
        short8 bk = *(const short8*)&Ks[(ni * 16 + lm) * 128 + kk * 32 + lq * 8];
        sa[ni] = __builtin_amdgcn_mfma_f32_16x16x32_bf16(aq[kk], bk, sa[ni], 0, 0, 0);
      }
    if (st == qt) {
#pragma unroll
      for (int ni = 0; ni < 4; ++ni)
#pragma unroll
        for (int r = 0; r < 4; ++r)
          if (ni * 16 + lm > w * 16 + lq * 4 + r) sa[ni][r] = -3.0e38f;
    }
    float rmax[4], alpha[4], rsum[4];
#pragma unroll
    for (int r = 0; r < 4; ++r)
      rmax[r] = fmaxf(fmaxf(sa[0][r], sa[1][r]), fmaxf(sa[2][r], sa[3][r]));
#pragma unroll
    for (int off = 1; off < 16; off <<= 1)
#pragma unroll
      for (int r = 0; r < 4; ++r)
        rmax[r] = fmaxf(rmax[r], __shfl_xor(rmax[r], off));
#pragma unroll
    for (int r = 0; r < 4; ++r) {
      const float mn = fmaxf(m4[r], rmax[r]);
      alpha[r] = __expf(m4[r] - mn);
      m4[r] = mn;
    }
#pragma unroll
    for (int ni = 0; ni < 4; ++ni)
#pragma unroll
      for (int r = 0; r < 4; ++r) sa[ni][r] = __expf(sa[ni][r] - m4[r]);
#pragma unroll
    for (int r = 0; r < 4; ++r)
      rsum[r] = sa[0][r] + sa[1][r] + sa[2][r] + sa[3][r];
#pragma unroll
    for (int off = 1; off < 16; off <<= 1)
#pragma unroll
      for (int r = 0; r < 4; ++r) rsum[r] += __shfl_xor(rsum[r], off);
#pragma unroll
    for (int r = 0; r < 4; ++r) l4[r] = l4[r] * alpha[r] + rsum[r];
    // P -> LDS (C-layout scatter), re-read in A-layout after barrier
#pragma unroll
    for (int ni = 0; ni < 4; ++ni)
#pragma unroll
      for (int r = 0; r < 4; ++r)
        Ps[w * 1280 + (lq * 4 + r) * 80 + ni * 16 + lm] = f2bf(sa[ni][r]);
#pragma unroll
    for (int i = 0; i < 8; ++i) {
      f32x4 a = acc[i];
      a[0] *= alpha[0]; a[1] *= alpha[1]; a[2] *= alpha[2]; a[3] *= alpha[3];
      acc[i] = a;
    }
    __syncthreads();
#pragma unroll
    for (int k2 = 0; k2 < 2; ++k2) {
      short8 ap = *(const short8*)&Ps[w * 1280 + lm * 80 + k2 * 32 + lq * 8];
#pragma unroll
      for (int ni = 0; ni < 8; ++ni) {
        short8 bv = *(const short8*)&Vs[(ni * 16 + lm) * 64 + k2 * 32 + lq * 8];
        acc[ni] = __builtin_amdgcn_mfma_f32_16x16x32_bf16(ap, bv, acc[ni], 0, 0, 0);
      }
    }
  }
  float linv[4];
#pragma unroll
  for (int r = 0; r < 4; ++r) linv[r] = 1.0f / l4[r];
#pragma unroll
  for (int ni = 0; ni < 8; ++ni)
#pragma unroll
    for (int r = 0; r < 4; ++r) {
      const int t = qt * 64 + w * 16 + lq * 4 + r;
      const int h = ni * 16 + lm;
      const float g = bf2f(qgb[((size_t)t * NH_ + n) * 256 + 128 + h]);
      const float o = acc[ni][r] * linv[r] * (1.0f / (1.0f + __expf(-g)));
      encb[((size_t)t * NH_ + n) * 128 + h] = f2bf(o);
    }
}

// ---------------------------------------------------------------------------
extern "C" void kernel_launch(void* const* d_in, const int* in_sizes, int n_in,
                              void* d_out, int out_size, void* d_ws, size_t ws_size,
                              hipStream_t stream)
{
  (void)in_sizes; (void)n_in; (void)out_size; (void)ws_size;
  const float* x0    = (const float*)d_in[0];
  const float* x1    = (const float*)d_in[1];
  const int*   pos   = (const int*)d_in[2];
  const float* qg_w0 = (const float*)d_in[4];
  const float* k_w0  = (const float*)d_in[5];
  const float* v_w0  = (const float*)d_in[6];
  const float* qn0   = (const float*)d_in[7];
  const float* kn0   = (const float*)d_in[8];
  const float* o_w0  = (const float*)d_in[9];
  const float* qg_w1 = (const float*)d_in[10];
  const float* k_w1  = (const float*)d_in[11];
  const float* v_w1  = (const float*)d_in[12];
  const float* qn1   = (const float*)d_in[13];
  const float* kn1   = (const float*)d_in[14];
  const float* o_w1  = (const float*)d_in[15];

  float* out    = (float*)d_out;
  float* kcache = out + (size_t)TT_ * WD_;
  float* vcache = kcache + (size_t)TT_ * KH_ * 128;

  // ws layout (bytes): wbuf 16M | xb 8M (-> Kb 2M + Vt 2M) | qgb 16M | encb 8M = 48M total
  ushort* wbuf = (ushort*)d_ws;
  ushort* xb   = wbuf + 8388608;
  ushort* qgb  = xb + 4194304;
  ushort* encb = qgb + 8388608;
  ushort* Kbuf = xb;                 // alias: valid after projection GEMMs
  ushort* Vtb  = xb + 1048576;

  convert_x<<<4096, 256, 0, stream>>>(x0, x1, xb);

  // qg projection (bf16 out), weights transposed through wbuf per stream
  convtrans<<<dim3(64, 8, 16), 256, 0, stream>>>(qg_w0, wbuf, WD_, 256);
  gemm_bf16<<<dim3(32, 4), 256, 0, stream>>>(xb, wbuf, nullptr, qgb, 4096);
  convtrans<<<dim3(64, 8, 16), 256, 0, stream>>>(qg_w1, wbuf, WD_, 256);
  gemm_bf16<<<dim3(32, 12), 256, 0, stream>>>(xb + (size_t)512 * 2048, wbuf, nullptr,
                                              qgb + (size_t)512 * 4096, 4096);
  // k/v projections (f32 out into caches)
  convtrans<<<dim3(64, 4, 4), 256, 0, stream>>>(k_w0, wbuf, WD_, 128);
  convtrans<<<dim3(64, 4, 4), 256, 0, stream>>>(k_w1, wbuf + 1048576, WD_, 128);
  convtrans<<<dim3(64, 4, 4), 256, 0, stream>>>(v_w0, wbuf + 2097152, WD_, 128);
  convtrans<<<dim3(64, 4, 4), 256, 0, stream>>>(v_w1, wbuf + 3145728, WD_, 128);
  gemm_bf16<<<dim3(4, 4),  256, 0, stream>>>(xb, wbuf, kcache, nullptr, 512);
  gemm_bf16<<<dim3(4, 12), 256, 0, stream>>>(xb + (size_t)512 * 2048, wbuf + 1048576,
                                             kcache + (size_t)512 * 512, nullptr, 512);
  gemm_bf16<<<dim3(4, 4),  256, 0, stream>>>(xb, wbuf + 2097152, vcache, nullptr, 512);
  gemm_bf16<<<dim3(4, 12), 256, 0, stream>>>(xb + (size_t)512 * 2048, wbuf + 3145728,
                                             vcache + (size_t)512 * 512, nullptr, 512);

  // norm + rope (kcache in place -> cached_k; Kb bf16 into xb alias)
  postproc<<<2048, 256, 0, stream>>>(qgb, kcache, Kbuf, pos, qn0, kn0, qn1, kn1);
  // Vt (kh*128+h, t) bf16 from vcache
  convtrans<<<dim3(64, 16, 1), 256, 0, stream>>>(vcache, Vtb, TT_, 512);

  attn<<<dim3(32, 16), 256, 0, stream>>>(qgb, Kbuf, Vtb, encb);

  // output projections
  convtrans<<<dim3(64, 64, 1), 256, 0, stream>>>(o_w0, wbuf, WD_, WD_);
  convtrans<<<dim3(64, 64, 1), 256, 0, stream>>>(o_w1, wbuf + 4194304, WD_, WD_);
  gemm_bf16<<<dim3(16, 4), 256, 0, stream>>>(encb, wbuf, out, nullptr, 2048);
  gemm_bf16<<<dim3(16, 12), 256, 0, stream>>>(encb + (size_t)512 * 2048, wbuf + 4194304,
                                              out + (size_t)512 * 2048, nullptr, 2048);
}

// Round 3
// 483.358 us; speedup vs baseline: 6.5538x; 1.4801x over previous
//
#include <hip/hip_runtime.h>
#include <hip/hip_bf16.h>
#include <cstdint>
#include <cstddef>

#define T0_ 512
#define TT_ 2048
#define WD_ 2048
#define NH_ 16
#define KH_ 4

typedef __attribute__((ext_vector_type(8))) short short8;
typedef __attribute__((ext_vector_type(4))) float f32x4;

#define AS1 __attribute__((address_space(1)))
#define AS3 __attribute__((address_space(3)))

__device__ __forceinline__ ushort f2bf(float x) {
  __hip_bfloat16 h = __float2bfloat16(x);
  ushort u; __builtin_memcpy(&u, &h, 2); return u;
}
__device__ __forceinline__ float bf2f(ushort u) {
  __hip_bfloat16 h; __builtin_memcpy(&h, &u, 2);
  return __bfloat162float(h);
}
__device__ __forceinline__ void g2l16(const ushort* g, AS3 ushort* s) {
  __builtin_amdgcn_global_load_lds((const AS1 uint32_t*)g, (AS3 uint32_t*)s, 16, 0, 0);
}

// ---------------------------------------------------------------------------
// x0/x1 (f32) -> xb (2048x2048 bf16)
__global__ __launch_bounds__(256) void convert_x(
    const float* __restrict__ x0, const float* __restrict__ x1, ushort* __restrict__ xb)
{
  const int i = blockIdx.x * 256 + threadIdx.x;
  const int e = i * 4;
  const int row = e >> 11, col = e & 2047;
  const float* src = (row < T0_) ? (x0 + (size_t)row * WD_ + col)
                                 : (x1 + (size_t)(row - T0_) * WD_ + col);
  const float4 v = *(const float4*)src;
  ushort4 o; o.x = f2bf(v.x); o.y = f2bf(v.y); o.z = f2bf(v.z); o.w = f2bf(v.w);
  *(ushort4*)(xb + e) = o;
}

// ---------------------------------------------------------------------------
// Transpose-convert, single source: in f32 (slab,R,C) -> out bf16 (slab,C,R)
__global__ __launch_bounds__(256) void convtrans(
    const float* __restrict__ in, ushort* __restrict__ out, int R, int C)
{
  __shared__ float tile[32][33];
  const int z = blockIdx.z;
  in  += (size_t)z * R * C;
  out += (size_t)z * R * C;
  const int r0 = blockIdx.x * 32, c0 = blockIdx.y * 32;
  const int tx = threadIdx.x & 31, ty = threadIdx.x >> 5;
#pragma unroll
  for (int i = 0; i < 4; ++i)
    tile[ty + 8 * i][tx] = in[(size_t)(r0 + ty + 8 * i) * C + c0 + tx];
  __syncthreads();
#pragma unroll
  for (int i = 0; i < 4; ++i)
    out[(size_t)(c0 + ty + 8 * i) * R + r0 + tx] = f2bf(tile[tx][ty + 8 * i]);
}

// Dual-source variant: z < half -> s0/d0 slab z, else s1/d1 slab z-half.
__global__ __launch_bounds__(256) void convtrans2(
    const float* __restrict__ s0, const float* __restrict__ s1,
    ushort* __restrict__ d0, ushort* __restrict__ d1, int R, int C, int half)
{
  __shared__ float tile[32][33];
  int z = blockIdx.z;
  const float* in; ushort* out;
  if (z < half) { in = s0 + (size_t)z * R * C; out = d0 + (size_t)z * R * C; }
  else { z -= half; in = s1 + (size_t)z * R * C; out = d1 + (size_t)z * R * C; }
  const int r0 = blockIdx.x * 32, c0 = blockIdx.y * 32;
  const int tx = threadIdx.x & 31, ty = threadIdx.x >> 5;
#pragma unroll
  for (int i = 0; i < 4; ++i)
    tile[ty + 8 * i][tx] = in[(size_t)(r0 + ty + 8 * i) * C + c0 + tx];
  __syncthreads();
#pragma unroll
  for (int i = 0; i < 4; ++i)
    out[(size_t)(c0 + ty + 8 * i) * R + r0 + tx] = f2bf(tile[tx][ty + 8 * i]);
}

// ---------------------------------------------------------------------------
// Shared MFMA GEMM core: 128x128 C tile, BK=32, 256 thr (4 waves 2x2).
// A, Bt row-major k-contiguous bf16, K = WD_ = 2048.
__device__ __forceinline__ void gemm_core(
    const ushort* __restrict__ A, const ushort* __restrict__ Bt,
    int row0, int col0, ushort* As, ushort* Bs, f32x4 (&acc)[4][4])
{
  const int tid = threadIdx.x;
  const int w = tid >> 6, l = tid & 63, lq = l >> 4, lm = l & 15;
  const int wr = (w >> 1) * 64, wc = (w & 1) * 64;
  const ushort* Ag = A + (size_t)(row0 + (tid >> 2)) * WD_ + (tid & 3) * 8;
  const ushort* Bg = Bt + (size_t)(col0 + (tid >> 2)) * WD_ + (tid & 3) * 8;
  AS3 ushort* AsW = (AS3 ushort*)As + w * 512;
  AS3 ushort* BsW = (AS3 ushort*)Bs + w * 512;

  for (int k0 = 0; k0 < WD_; k0 += 32) {
    __syncthreads();
    g2l16(Ag + k0, AsW);
    g2l16(Ag + (size_t)64 * WD_ + k0, AsW + 2048);
    g2l16(Bg + k0, BsW);
    g2l16(Bg + (size_t)64 * WD_ + k0, BsW + 2048);
    __syncthreads();
    short8 af[4], bfr[4];
#pragma unroll
    for (int mi = 0; mi < 4; ++mi)
      af[mi] = *(const short8*)&As[(wr + mi * 16 + lm) * 32 + lq * 8];
#pragma unroll
    for (int ni = 0; ni < 4; ++ni)
      bfr[ni] = *(const short8*)&Bs[(wc + ni * 16 + lm) * 32 + lq * 8];
#pragma unroll
    for (int mi = 0; mi < 4; ++mi)
#pragma unroll
      for (int ni = 0; ni < 4; ++ni)
        acc[mi][ni] = __builtin_amdgcn_mfma_f32_16x16x32_bf16(af[mi], bfr[ni], acc[mi][ni], 0, 0, 0);
  }
}

// qg projection: C bf16 (t, 4096), weight by stream (row block).
__global__ __launch_bounds__(256) void gemm_qg(
    const ushort* __restrict__ A, const ushort* __restrict__ W0t,
    const ushort* __restrict__ W1t, ushort* __restrict__ C)
{
  __shared__ ushort As[4096], Bs[4096];
  const int row0 = blockIdx.y * 128, col0 = blockIdx.x * 128;
  const ushort* Bt = (row0 < T0_) ? W0t : W1t;
  f32x4 acc[4][4];
#pragma unroll
  for (int mi = 0; mi < 4; ++mi)
#pragma unroll
    for (int ni = 0; ni < 4; ++ni) acc[mi][ni] = (f32x4){0.f, 0.f, 0.f, 0.f};
  gemm_core(A, Bt, row0, col0, As, Bs, acc);
  const int w = threadIdx.x >> 6, l = threadIdx.x & 63, lq = l >> 4, lm = l & 15;
  const int wr = (w >> 1) * 64, wc = (w & 1) * 64;
#pragma unroll
  for (int mi = 0; mi < 4; ++mi)
#pragma unroll
    for (int ni = 0; ni < 4; ++ni)
#pragma unroll
      for (int r = 0; r < 4; ++r) {
        const size_t rr = (size_t)row0 + wr + mi * 16 + lq * 4 + r;
        const size_t cc = (size_t)col0 + wc + ni * 16 + lm;
        C[rr * 4096 + cc] = f2bf(acc[mi][ni][r]);
      }
}

// k+v projections: grid (8, 16); col tile <4 -> kcache, else vcache (f32, ldc 512)
__global__ __launch_bounds__(256) void gemm_kv(
    const ushort* __restrict__ A,
    const ushort* __restrict__ k0t, const ushort* __restrict__ k1t,
    const ushort* __restrict__ v0t, const ushort* __restrict__ v1t,
    float* __restrict__ kc, float* __restrict__ vc)
{
  __shared__ ushort As[4096], Bs[4096];
  const int row0 = blockIdx.y * 128;
  const int ct = blockIdx.x;
  const bool isv = (ct >= 4);
  const int col0 = (ct & 3) * 128;
  const ushort* Bt = isv ? ((row0 < T0_) ? v0t : v1t) : ((row0 < T0_) ? k0t : k1t);
  float* Cf = isv ? vc : kc;
  f32x4 acc[4][4];
#pragma unroll
  for (int mi = 0; mi < 4; ++mi)
#pragma unroll
    for (int ni = 0; ni < 4; ++ni) acc[mi][ni] = (f32x4){0.f, 0.f, 0.f, 0.f};
  gemm_core(A, Bt, row0, col0, As, Bs, acc);
  const int w = threadIdx.x >> 6, l = threadIdx.x & 63, lq = l >> 4, lm = l & 15;
  const int wr = (w >> 1) * 64, wc = (w & 1) * 64;
#pragma unroll
  for (int mi = 0; mi < 4; ++mi)
#pragma unroll
    for (int ni = 0; ni < 4; ++ni)
#pragma unroll
      for (int r = 0; r < 4; ++r) {
        const size_t rr = (size_t)row0 + wr + mi * 16 + lq * 4 + r;
        const size_t cc = (size_t)col0 + wc + ni * 16 + lm;
        Cf[rr * 512 + cc] = acc[mi][ni][r];
      }
}

// out projection: grid (16, 16); C f32 (t, 2048), weight by stream.
__global__ __launch_bounds__(256) void gemm_out(
    const ushort* __restrict__ A, const ushort* __restrict__ W0t,
    const ushort* __restrict__ W1t, float* __restrict__ C)
{
  __shared__ ushort As[4096], Bs[4096];
  const int row0 = blockIdx.y * 128, col0 = blockIdx.x * 128;
  const ushort* Bt = (row0 < T0_) ? W0t : W1t;
  f32x4 acc[4][4];
#pragma unroll
  for (int mi = 0; mi < 4; ++mi)
#pragma unroll
    for (int ni = 0; ni < 4; ++ni) acc[mi][ni] = (f32x4){0.f, 0.f, 0.f, 0.f};
  gemm_core(A, Bt, row0, col0, As, Bs, acc);
  const int w = threadIdx.x >> 6, l = threadIdx.x & 63, lq = l >> 4, lm = l & 15;
  const int wr = (w >> 1) * 64, wc = (w & 1) * 64;
#pragma unroll
  for (int mi = 0; mi < 4; ++mi)
#pragma unroll
    for (int ni = 0; ni < 4; ++ni)
#pragma unroll
      for (int r = 0; r < 4; ++r) {
        const size_t rr = (size_t)row0 + wr + mi * 16 + lq * 4 + r;
        const size_t cc = (size_t)col0 + wc + ni * 16 + lm;
        C[rr * 2048 + cc] = acc[mi][ni][r];
      }
}

// ---------------------------------------------------------------------------
// RMSNorm + RoPE (+ q scale). qgb bf16 (t,n,256) q in-place; kcache f32
// in-place (this IS cached_k) + bf16 copy Kb (t,kh,128).
__global__ __launch_bounds__(256) void postproc(
    ushort* __restrict__ qgb, float* __restrict__ kc, ushort* __restrict__ Kb,
    const int* __restrict__ positions,
    const float* __restrict__ qn0, const float* __restrict__ kn0,
    const float* __restrict__ qn1, const float* __restrict__ kn1)
{
  const int t = blockIdx.x;
  const int w = threadIdx.x >> 6, l = threadIdx.x & 63;
  const float pos = (float)positions[t];
  const bool str1 = (t >= T0_);
  const float* qn = str1 ? qn1 : qn0;
  const float* kn = str1 ? kn1 : kn0;
  const float kfreq = 13.815510557964274f / 32.0f;  // ln(1e6)/32
  const int h0 = 2 * l, h1 = 2 * l + 1;

  for (int r = w; r < NH_ + KH_; r += 4) {
    const bool isq = (r < NH_);
    float v0, v1; size_t bi; const float* sc;
    if (isq) {
      bi = ((size_t)t * NH_ + r) * 256;
      v0 = bf2f(qgb[bi + h0]); v1 = bf2f(qgb[bi + h1]); sc = qn;
    } else {
      bi = ((size_t)t * KH_ + (r - NH_)) * 128;
      v0 = kc[bi + h0]; v1 = kc[bi + h1]; sc = kn;
    }
    float ss = v0 * v0 + v1 * v1;
#pragma unroll
    for (int off = 32; off > 0; off >>= 1) ss += __shfl_xor(ss, off);
    const float rstd = rsqrtf(ss * (1.0f / 128.0f) + 1e-6f);
    v0 = v0 * rstd * (1.0f + sc[h0]);
    v1 = v1 * rstd * (1.0f + sc[h1]);
    const float p0 = __shfl_xor(v0, 16);
    const float p1 = __shfl_xor(v1, 16);
    if (l < 32) {
      const int i0 = (l < 16) ? h0 : (h0 - 32);
      const float a0 = pos * __expf(-(float)i0 * kfreq);
      const float a1 = pos * __expf(-(float)(i0 + 1) * kfreq);
      const float c0 = cosf(a0), s0 = sinf(a0);
      const float c1 = cosf(a1), s1v = sinf(a1);
      if (l < 16) { v0 = v0 * c0 - p0 * s0; v1 = v1 * c1 - p1 * s1v; }
      else        { v0 = v0 * c0 + p0 * s0; v1 = v1 * c1 + p1 * s1v; }
    }
    if (isq) {
      v0 *= 0.08838834764831843f; v1 *= 0.08838834764831843f;
      qgb[bi + h0] = f2bf(v0); qgb[bi + h1] = f2bf(v1);
    } else {
      kc[bi + h0] = v0; kc[bi + h1] = v1;
      Kb[bi + h0] = f2bf(v0); Kb[bi + h1] = f2bf(v1);
    }
  }
}

// ---------------------------------------------------------------------------
// Flash attention, MFMA, double-buffered K/V prefetch.
// qgb: normed q + raw gate bf16 (t,n,256); Kb (t,kh,128); Vt (kh,128,2048).
// encb out bf16 (t, n*128+h).
__global__ __launch_bounds__(256) void attn(
    const ushort* __restrict__ qgb, const ushort* __restrict__ Kb,
    const ushort* __restrict__ Vt, ushort* __restrict__ encb)
{
  __shared__ ushort Ks[2 * 64 * 128];   // [buf][s][h]
  __shared__ ushort Vs[2 * 128 * 64];   // [buf][h][s]
  __shared__ ushort Ps[4 * 16 * 80];    // per-wave 16x64, rowstride 80
  const int tid = threadIdx.x;
  const int w = tid >> 6, l = tid & 63, lq = l >> 4, lm = l & 15;
  const int qt = (int)gridDim.x - 1 - (int)blockIdx.x;  // heavy blocks first
  const int n = blockIdx.y, kh = n >> 2;

  short8 aq[4];
  {
    const ushort* qb = qgb + ((size_t)(qt * 64 + w * 16 + lm) * NH_ + n) * 256 + lq * 8;
#pragma unroll
    for (int kk = 0; kk < 4; ++kk) aq[kk] = *(const short8*)(qb + kk * 32);
  }
  f32x4 acc[8];
#pragma unroll
  for (int i = 0; i < 8; ++i) acc[i] = (f32x4){0.f, 0.f, 0.f, 0.f};
  float m4[4] = {-3.0e38f, -3.0e38f, -3.0e38f, -3.0e38f};
  float l4[4] = {0.f, 0.f, 0.f, 0.f};

  AS3 ushort* KsW = (AS3 ushort*)Ks + w * 512;
  AS3 ushort* VsW = (AS3 ushort*)Vs + w * 512;
  const ushort* Kg = Kb + ((size_t)(tid >> 4) * KH_ + kh) * 128 + (tid & 15) * 8;
  const ushort* Vg = Vt + ((size_t)kh * 128 + (tid >> 3)) * TT_ + (tid & 7) * 8;

  // stage st = 0 into buffer 0
#pragma unroll
  for (int c = 0; c < 4; ++c) {
    g2l16(Kg + (size_t)(16 * c) * (KH_ * 128), KsW + c * 2048);
    g2l16(Vg + (size_t)(32 * c) * TT_, VsW + c * 2048);
  }

  for (int st = 0; st <= qt; ++st) {
    const int buf = st & 1;
    __syncthreads();  // stage(st) complete (vmcnt drain) + prev reads done
    if (st < qt) {    // prefetch st+1 into the other buffer
      const int s0n = (st + 1) * 64;
      const int bo = (buf ^ 1) * 8192;
#pragma unroll
      for (int c = 0; c < 4; ++c) {
        g2l16(Kg + (size_t)(s0n + 16 * c) * (KH_ * 128), KsW + bo + c * 2048);
        g2l16(Vg + (size_t)(32 * c) * TT_ + s0n, VsW + bo + c * 2048);
      }
    }
    const ushort* Ksb = Ks + buf * 8192;
    const ushort* Vsb = Vs + buf * 8192;

    f32x4 sa[4];
#pragma unroll
    for (int ni = 0; ni < 4; ++ni) sa[ni] = (f32x4){0.f, 0.f, 0.f, 0.f};
#pragma unroll
    for (int kk = 0; kk < 4; ++kk)
#pragma unroll
      for (int ni = 0; ni < 4; ++ni) {
        short8 bk = *(const short8*)&Ksb[(ni * 16 + lm) * 128 + kk * 32 + lq * 8];
        sa[ni] = __builtin_amdgcn_mfma_f32_16x16x32_bf16(aq[kk], bk, sa[ni], 0, 0, 0);
      }
    if (st == qt) {
#pragma unroll
      for (int ni = 0; ni < 4; ++ni)
#pragma unroll
        for (int r = 0; r < 4; ++r)
          if (ni * 16 + lm > w * 16 + lq * 4 + r) sa[ni][r] = -3.0e38f;
    }
    float rmax[4], alpha[4], rsum[4];
#pragma unroll
    for (int r = 0; r < 4; ++r)
      rmax[r] = fmaxf(fmaxf(sa[0][r], sa[1][r]), fmaxf(sa[2][r], sa[3][r]));
#pragma unroll
    for (int off = 1; off < 16; off <<= 1)
#pragma unroll
      for (int r = 0; r < 4; ++r)
        rmax[r] = fmaxf(rmax[r], __shfl_xor(rmax[r], off));
#pragma unroll
    for (int r = 0; r < 4; ++r) {
      const float mn = fmaxf(m4[r], rmax[r]);
      alpha[r] = __expf(m4[r] - mn);
      m4[r] = mn;
    }
#pragma unroll
    for (int ni = 0; ni < 4; ++ni)
#pragma unroll
      for (int r = 0; r < 4; ++r) sa[ni][r] = __expf(sa[ni][r] - m4[r]);
#pragma unroll
    for (int r = 0; r < 4; ++r)
      rsum[r] = sa[0][r] + sa[1][r] + sa[2][r] + sa[3][r];
#pragma unroll
    for (int off = 1; off < 16; off <<= 1)
#pragma unroll
      for (int r = 0; r < 4; ++r) rsum[r] += __shfl_xor(rsum[r], off);
#pragma unroll
    for (int r = 0; r < 4; ++r) l4[r] = l4[r] * alpha[r] + rsum[r];

    // P: C-layout -> LDS -> A-layout (per-wave region; intra-wave lgkmcnt
    // ordering suffices, no block barrier needed)
#pragma unroll
    for (int ni = 0; ni < 4; ++ni)
#pragma unroll
      for (int r = 0; r < 4; ++r)
        Ps[w * 1280 + (lq * 4 + r) * 80 + ni * 16 + lm] = f2bf(sa[ni][r]);
#pragma unroll
    for (int i = 0; i < 8; ++i) {
      f32x4 a = acc[i];
      a[0] *= alpha[0]; a[1] *= alpha[1]; a[2] *= alpha[2]; a[3] *= alpha[3];
      acc[i] = a;
    }
#pragma unroll
    for (int k2 = 0; k2 < 2; ++k2) {
      short8 ap = *(const short8*)&Ps[w * 1280 + lm * 80 + k2 * 32 + lq * 8];
#pragma unroll
      for (int ni = 0; ni < 8; ++ni) {
        short8 bv = *(const short8*)&Vsb[(ni * 16 + lm) * 64 + k2 * 32 + lq * 8];
        acc[ni] = __builtin_amdgcn_mfma_f32_16x16x32_bf16(ap, bv, acc[ni], 0, 0, 0);
      }
    }
  }
  float linv[4];
#pragma unroll
  for (int r = 0; r < 4; ++r) linv[r] = 1.0f / l4[r];
#pragma unroll
  for (int ni = 0; ni < 8; ++ni)
#pragma unroll
    for (int r = 0; r < 4; ++r) {
      const int t = qt * 64 + w * 16 + lq * 4 + r;
      const int h = ni * 16 + lm;
      const float g = bf2f(qgb[((size_t)t * NH_ + n) * 256 + 128 + h]);
      const float o = acc[ni][r] * linv[r] * (1.0f / (1.0f + __expf(-g)));
      encb[((size_t)t * NH_ + n) * 128 + h] = f2bf(o);
    }
}

// ---------------------------------------------------------------------------
extern "C" void kernel_launch(void* const* d_in, const int* in_sizes, int n_in,
                              void* d_out, int out_size, void* d_ws, size_t ws_size,
                              hipStream_t stream)
{
  (void)in_sizes; (void)n_in; (void)out_size; (void)ws_size;
  const float* x0    = (const float*)d_in[0];
  const float* x1    = (const float*)d_in[1];
  const int*   pos   = (const int*)d_in[2];
  const float* qg_w0 = (const float*)d_in[4];
  const float* k_w0  = (const float*)d_in[5];
  const float* v_w0  = (const float*)d_in[6];
  const float* qn0   = (const float*)d_in[7];
  const float* kn0   = (const float*)d_in[8];
  const float* o_w0  = (const float*)d_in[9];
  const float* qg_w1 = (const float*)d_in[10];
  const float* k_w1  = (const float*)d_in[11];
  const float* v_w1  = (const float*)d_in[12];
  const float* qn1   = (const float*)d_in[13];
  const float* kn1   = (const float*)d_in[14];
  const float* o_w1  = (const float*)d_in[15];

  float* out    = (float*)d_out;
  float* kcache = out + (size_t)TT_ * WD_;
  float* vcache = kcache + (size_t)TT_ * KH_ * 128;
  // out0/out1 region (16 MiB) doubles as scratch for qg_w0^T until gemm_out.
  ushort* qsc = (ushort*)d_out;

  // ws: wbuf 16M | xb 8M (-> Kb 2M + Vt 2M after projections) | qgb 16M | encb 8M
  ushort* wbuf = (ushort*)d_ws;
  ushort* xb   = wbuf + 8388608;
  ushort* qgb  = xb + 4194304;
  ushort* encb = qgb + 8388608;
  ushort* Kbuf = xb;
  ushort* Vtb  = xb + 1048576;
  ushort* k0t = encb, *k1t = encb + 1048576, *v0t = encb + 2097152, *v1t = encb + 3145728;

  convert_x<<<4096, 256, 0, stream>>>(x0, x1, xb);

  // weight transposes
  convtrans2<<<dim3(64, 8, 32), 256, 0, stream>>>(qg_w0, qg_w1, qsc, wbuf, WD_, 256, 16);
  convtrans2<<<dim3(64, 4, 8), 256, 0, stream>>>(k_w0, k_w1, k0t, k1t, WD_, 128, 4);
  convtrans2<<<dim3(64, 4, 8), 256, 0, stream>>>(v_w0, v_w1, v0t, v1t, WD_, 128, 4);

  // projections
  gemm_qg<<<dim3(32, 16), 256, 0, stream>>>(xb, qsc, wbuf, qgb);
  gemm_kv<<<dim3(8, 16), 256, 0, stream>>>(xb, k0t, k1t, v0t, v1t, kcache, vcache);

  // norm + rope (kcache in place -> cached_k; Kb bf16 into xb alias)
  postproc<<<2048, 256, 0, stream>>>(qgb, kcache, Kbuf, pos, qn0, kn0, qn1, kn1);
  // Vt (kh*128+h, t) bf16 from vcache
  convtrans<<<dim3(64, 16, 1), 256, 0, stream>>>(vcache, Vtb, TT_, 512);

  attn<<<dim3(32, 16), 256, 0, stream>>>(qgb, Kbuf, Vtb, encb);

  // output projection (o_w^T both streams into wbuf; qg weights dead)
  convtrans2<<<dim3(64, 64, 2), 256, 0, stream>>>(o_w0, o_w1, wbuf, wbuf + 4194304, WD_, WD_, 1);
  gemm_out<<<dim3(16, 16), 256, 0, stream>>>(encb, wbuf, wbuf + 4194304, out);
}

// Round 5
// 399.347 us; speedup vs baseline: 7.9326x; 1.2104x over previous
//
#include <hip/hip_runtime.h>
#include <hip/hip_bf16.h>
#include <cstdint>
#include <cstddef>

#define T0_ 512
#define TT_ 2048
#define WD_ 2048
#define NH_ 16
#define KH_ 4

typedef __attribute__((ext_vector_type(8))) short short8;
typedef __attribute__((ext_vector_type(4))) short short4v;
typedef __attribute__((ext_vector_type(4))) float f32x4;

#define AS1 __attribute__((address_space(1)))
#define AS3 __attribute__((address_space(3)))

__device__ __forceinline__ ushort f2bf(float x) {
  __hip_bfloat16 h = __float2bfloat16(x);
  ushort u; __builtin_memcpy(&u, &h, 2); return u;
}
__device__ __forceinline__ float bf2f(ushort u) {
  __hip_bfloat16 h; __builtin_memcpy(&h, &u, 2);
  return __bfloat162float(h);
}
__device__ __forceinline__ void g2l16(const ushort* g, AS3 ushort* s) {
  __builtin_amdgcn_global_load_lds((const AS1 uint32_t*)g, (AS3 uint32_t*)s, 16, 0, 0);
}

// ---------------------------------------------------------------------------
// x0/x1 (f32) -> xb (2048x2048 bf16)
__global__ __launch_bounds__(256) void convert_x(
    const float* __restrict__ x0, const float* __restrict__ x1, ushort* __restrict__ xb)
{
  const int i = blockIdx.x * 256 + threadIdx.x;
  const int e = i * 4;
  const int row = e >> 11, col = e & 2047;
  const float* src = (row < T0_) ? (x0 + (size_t)row * WD_ + col)
                                 : (x1 + (size_t)(row - T0_) * WD_ + col);
  const float4 v = *(const float4*)src;
  ushort4 o; o.x = f2bf(v.x); o.y = f2bf(v.y); o.z = f2bf(v.z); o.w = f2bf(v.w);
  *(ushort4*)(xb + e) = o;
}

// ---------------------------------------------------------------------------
// Transpose-convert: in f32 (slab,R,C) -> out bf16 (slab,C,R)
__global__ __launch_bounds__(256) void convtrans(
    const float* __restrict__ in, ushort* __restrict__ out, int R, int C)
{
  __shared__ float tile[32][33];
  const int z = blockIdx.z;
  in  += (size_t)z * R * C;
  out += (size_t)z * R * C;
  const int r0 = blockIdx.x * 32, c0 = blockIdx.y * 32;
  const int tx = threadIdx.x & 31, ty = threadIdx.x >> 5;
#pragma unroll
  for (int i = 0; i < 4; ++i)
    tile[ty + 8 * i][tx] = in[(size_t)(r0 + ty + 8 * i) * C + c0 + tx];
  __syncthreads();
#pragma unroll
  for (int i = 0; i < 4; ++i)
    out[(size_t)(c0 + ty + 8 * i) * R + r0 + tx] = f2bf(tile[tx][ty + 8 * i]);
}

// Dual-source variant: z < half -> s0/d0 slab z, else s1/d1 slab z-half.
__global__ __launch_bounds__(256) void convtrans2(
    const float* __restrict__ s0, const float* __restrict__ s1,
    ushort* __restrict__ d0, ushort* __restrict__ d1, int R, int C, int half)
{
  __shared__ float tile[32][33];
  int z = blockIdx.z;
  const float* in; ushort* out;
  if (z < half) { in = s0 + (size_t)z * R * C; out = d0 + (size_t)z * R * C; }
  else { z -= half; in = s1 + (size_t)z * R * C; out = d1 + (size_t)z * R * C; }
  const int r0 = blockIdx.x * 32, c0 = blockIdx.y * 32;
  const int tx = threadIdx.x & 31, ty = threadIdx.x >> 5;
#pragma unroll
  for (int i = 0; i < 4; ++i)
    tile[ty + 8 * i][tx] = in[(size_t)(r0 + ty + 8 * i) * C + c0 + tx];
  __syncthreads();
#pragma unroll
  for (int i = 0; i < 4; ++i)
    out[(size_t)(c0 + ty + 8 * i) * R + r0 + tx] = f2bf(tile[tx][ty + 8 * i]);
}

// ---------------------------------------------------------------------------
// Shared MFMA GEMM core: 128x128 C tile, BK=32, 256 thr (4 waves 2x2).
__device__ __forceinline__ void gemm_core(
    const ushort* __restrict__ A, const ushort* __restrict__ Bt,
    int row0, int col0, ushort* As, ushort* Bs, f32x4 (&acc)[4][4])
{
  const int tid = threadIdx.x;
  const int w = tid >> 6, l = tid & 63, lq = l >> 4, lm = l & 15;
  const int wr = (w >> 1) * 64, wc = (w & 1) * 64;
  const ushort* Ag = A + (size_t)(row0 + (tid >> 2)) * WD_ + (tid & 3) * 8;
  const ushort* Bg = Bt + (size_t)(col0 + (tid >> 2)) * WD_ + (tid & 3) * 8;
  AS3 ushort* AsW = (AS3 ushort*)As + w * 512;
  AS3 ushort* BsW = (AS3 ushort*)Bs + w * 512;

  for (int k0 = 0; k0 < WD_; k0 += 32) {
    __syncthreads();
    g2l16(Ag + k0, AsW);
    g2l16(Ag + (size_t)64 * WD_ + k0, AsW + 2048);
    g2l16(Bg + k0, BsW);
    g2l16(Bg + (size_t)64 * WD_ + k0, BsW + 2048);
    __syncthreads();
    short8 af[4], bfr[4];
#pragma unroll
    for (int mi = 0; mi < 4; ++mi)
      af[mi] = *(const short8*)&As[(wr + mi * 16 + lm) * 32 + lq * 8];
#pragma unroll
    for (int ni = 0; ni < 4; ++ni)
      bfr[ni] = *(const short8*)&Bs[(wc + ni * 16 + lm) * 32 + lq * 8];
#pragma unroll
    for (int mi = 0; mi < 4; ++mi)
#pragma unroll
      for (int ni = 0; ni < 4; ++ni)
        acc[mi][ni] = __builtin_amdgcn_mfma_f32_16x16x32_bf16(af[mi], bfr[ni], acc[mi][ni], 0, 0, 0);
  }
}

// ---------------------------------------------------------------------------
// All projections in one launch. grid (40, 16):
//  bx<32: qg (bf16, ldc 4096) | bx 32..35: k->kcache f32 | bx 36..39: v->vcache f32
__global__ __launch_bounds__(256) void gemm_proj(
    const ushort* __restrict__ A,
    const ushort* __restrict__ qg0t, const ushort* __restrict__ qg1t,
    const ushort* __restrict__ k0t,  const ushort* __restrict__ k1t,
    const ushort* __restrict__ v0t,  const ushort* __restrict__ v1t,
    ushort* __restrict__ Cqg, float* __restrict__ kc, float* __restrict__ vc)
{
  __shared__ ushort As[4096], Bs[4096];
  const int bx = blockIdx.x;
  const int row0 = blockIdx.y * 128;
  const bool s1 = (row0 >= T0_);
  const ushort* Bt; int col0;
  float* Cf = nullptr; ushort* Cb = nullptr; int ldc;
  if (bx < 32) {
    Bt = s1 ? qg1t : qg0t; col0 = bx * 128; Cb = Cqg; ldc = 4096;
  } else if (bx < 36) {
    Bt = s1 ? k1t : k0t; col0 = (bx - 32) * 128; Cf = kc; ldc = 512;
  } else {
    Bt = s1 ? v1t : v0t; col0 = (bx - 36) * 128; Cf = vc; ldc = 512;
  }
  f32x4 acc[4][4];
#pragma unroll
  for (int mi = 0; mi < 4; ++mi)
#pragma unroll
    for (int ni = 0; ni < 4; ++ni) acc[mi][ni] = (f32x4){0.f, 0.f, 0.f, 0.f};
  gemm_core(A, Bt, row0, col0, As, Bs, acc);
  const int w = threadIdx.x >> 6, l = threadIdx.x & 63, lq = l >> 4, lm = l & 15;
  const int wr = (w >> 1) * 64, wc = (w & 1) * 64;
#pragma unroll
  for (int mi = 0; mi < 4; ++mi)
#pragma unroll
    for (int ni = 0; ni < 4; ++ni)
#pragma unroll
      for (int r = 0; r < 4; ++r) {
        const size_t rr = (size_t)row0 + wr + mi * 16 + lq * 4 + r;
        const size_t cc = (size_t)col0 + wc + ni * 16 + lm;
        if (Cb) Cb[rr * ldc + cc] = f2bf(acc[mi][ni][r]);
        else    Cf[rr * ldc + cc] = acc[mi][ni][r];
      }
}

// out projection: grid (16, 16); C f32 (t, 2048), weight by stream.
__global__ __launch_bounds__(256) void gemm_out(
    const ushort* __restrict__ A, const ushort* __restrict__ W0t,
    const ushort* __restrict__ W1t, float* __restrict__ C)
{
  __shared__ ushort As[4096], Bs[4096];
  const int row0 = blockIdx.y * 128, col0 = blockIdx.x * 128;
  const ushort* Bt = (row0 < T0_) ? W0t : W1t;
  f32x4 acc[4][4];
#pragma unroll
  for (int mi = 0; mi < 4; ++mi)
#pragma unroll
    for (int ni = 0; ni < 4; ++ni) acc[mi][ni] = (f32x4){0.f, 0.f, 0.f, 0.f};
  gemm_core(A, Bt, row0, col0, As, Bs, acc);
  const int w = threadIdx.x >> 6, l = threadIdx.x & 63, lq = l >> 4, lm = l & 15;
  const int wr = (w >> 1) * 64, wc = (w & 1) * 64;
#pragma unroll
  for (int mi = 0; mi < 4; ++mi)
#pragma unroll
    for (int ni = 0; ni < 4; ++ni)
#pragma unroll
      for (int r = 0; r < 4; ++r) {
        const size_t rr = (size_t)row0 + wr + mi * 16 + lq * 4 + r;
        const size_t cc = (size_t)col0 + wc + ni * 16 + lm;
        C[rr * 2048 + cc] = acc[mi][ni][r];
      }
}

// ---------------------------------------------------------------------------
// RMSNorm + RoPE (+ q scale).
__global__ __launch_bounds__(256) void postproc(
    ushort* __restrict__ qgb, float* __restrict__ kc, ushort* __restrict__ Kb,
    const int* __restrict__ positions,
    const float* __restrict__ qn0, const float* __restrict__ kn0,
    const float* __restrict__ qn1, const float* __restrict__ kn1)
{
  const int t = blockIdx.x;
  const int w = threadIdx.x >> 6, l = threadIdx.x & 63;
  const float pos = (float)positions[t];
  const bool str1 = (t >= T0_);
  const float* qn = str1 ? qn1 : qn0;
  const float* kn = str1 ? kn1 : kn0;
  const float kfreq = 13.815510557964274f / 32.0f;  // ln(1e6)/32
  const int h0 = 2 * l, h1 = 2 * l + 1;

  for (int r = w; r < NH_ + KH_; r += 4) {
    const bool isq = (r < NH_);
    float v0, v1; size_t bi; const float* sc;
    if (isq) {
      bi = ((size_t)t * NH_ + r) * 256;
      v0 = bf2f(qgb[bi + h0]); v1 = bf2f(qgb[bi + h1]); sc = qn;
    } else {
      bi = ((size_t)t * KH_ + (r - NH_)) * 128;
      v0 = kc[bi + h0]; v1 = kc[bi + h1]; sc = kn;
    }
    float ss = v0 * v0 + v1 * v1;
#pragma unroll
    for (int off = 32; off > 0; off >>= 1) ss += __shfl_xor(ss, off);
    const float rstd = rsqrtf(ss * (1.0f / 128.0f) + 1e-6f);
    v0 = v0 * rstd * (1.0f + sc[h0]);
    v1 = v1 * rstd * (1.0f + sc[h1]);
    const float p0 = __shfl_xor(v0, 16);
    const float p1 = __shfl_xor(v1, 16);
    if (l < 32) {
      const int i0 = (l < 16) ? h0 : (h0 - 32);
      const float a0 = pos * __expf(-(float)i0 * kfreq);
      const float a1 = pos * __expf(-(float)(i0 + 1) * kfreq);
      const float c0 = cosf(a0), s0 = sinf(a0);
      const float c1 = cosf(a1), s1v = sinf(a1);
      if (l < 16) { v0 = v0 * c0 - p0 * s0; v1 = v1 * c1 - p1 * s1v; }
      else        { v0 = v0 * c0 + p0 * s0; v1 = v1 * c1 + p1 * s1v; }
    }
    if (isq) {
      v0 *= 0.08838834764831843f; v1 *= 0.08838834764831843f;
      qgb[bi + h0] = f2bf(v0); qgb[bi + h1] = f2bf(v1);
    } else {
      kc[bi + h0] = v0; kc[bi + h1] = v1;
      Kb[bi + h0] = f2bf(v0); Kb[bi + h1] = f2bf(v1);
    }
  }
}

// ---------------------------------------------------------------------------
// Flash attention, S^T formulation, XOR-swizzled LDS, balanced qt-pairs.
// Block (bx, n): tiles qt = bx and qt = 31-bx (64 q rows each), 128-s K/V steps.
// qgb: normed q + raw gate bf16 (t,n,256); Kb (t,kh,128); Vt (kh,128,2048).
__global__ __launch_bounds__(256) void attn(
    const ushort* __restrict__ qgb, const ushort* __restrict__ Kb,
    const ushort* __restrict__ Vt, ushort* __restrict__ encb)
{
  __shared__ ushort Ks[2 * 16384];  // [buf][s 0..127][h 0..127], 16B chunks ^ (s&15)
  __shared__ ushort Vs[2 * 16384];  // [buf][h 0..127][s 0..127], 16B chunks ^ (h&15)
  __shared__ ushort Ps[4 * 2048];   // per-wave [q 0..15][s 0..127], 8B units ^ lm
  const int tid = threadIdx.x;
  const int w = tid >> 6, l = tid & 63, lq = l >> 4, lm = l & 15;
  const int n = blockIdx.y, kh = n >> 2;

  auto stage = [&](int buf, int s0) {
#pragma unroll
    for (int c = 0; c < 8; ++c) {
      const int row = w * 32 + c * 4 + lq;
      const int ch = lm ^ (row & 15);
      const int dst = buf * 16384 + (w * 32 + c * 4) * 128;
      g2l16(Kb + (size_t)(s0 + row) * 512 + kh * 128 + ch * 8, (AS3 ushort*)Ks + dst);
      g2l16(Vt + (size_t)(kh * 128 + row) * 2048 + s0 + ch * 8, (AS3 ushort*)Vs + dst);
    }
  };

  for (int half = 0; half < 2; ++half) {
    const int qt = half ? (31 - (int)blockIdx.x) : (int)blockIdx.x;
    const int qtb = qt * 64;
    const int nst = qt / 2 + 1;

    short8 aq[4];
    {
      const ushort* qb = qgb + ((size_t)(qtb + w * 16 + lm) * NH_ + n) * 256 + lq * 8;
#pragma unroll
      for (int kk = 0; kk < 4; ++kk) aq[kk] = *(const short8*)(qb + kk * 32);
    }
    f32x4 acc[8];
#pragma unroll
    for (int i = 0; i < 8; ++i) acc[i] = (f32x4){0.f, 0.f, 0.f, 0.f};
    float mq = -3.0e38f, lsum = 0.0f;  // softmax state for q = qtb + w*16 + lm

    __syncthreads();  // prior tile's LDS reads complete
    stage(0, 0);

    for (int st = 0; st < nst; ++st) {
      const int buf = st & 1;
      const int s0 = st * 128;
      __syncthreads();  // stage(st) visible
      if (st + 1 < nst) stage(buf ^ 1, s0 + 128);
      const ushort* Kt = Ks + buf * 16384;
      const ushort* Vb = Vs + buf * 16384;

      // S^T = K * Q^T : D[m=s][n=q]
      f32x4 sa[8];
#pragma unroll
      for (int mi = 0; mi < 8; ++mi) sa[mi] = (f32x4){0.f, 0.f, 0.f, 0.f};
#pragma unroll
      for (int kk = 0; kk < 4; ++kk)
#pragma unroll
        for (int mi = 0; mi < 8; ++mi) {
          const short8 ak = *(const short8*)&Kt[(mi * 16 + lm) * 128 + ((kk * 4 + lq) ^ lm) * 8];
          sa[mi] = __builtin_amdgcn_mfma_f32_16x16x32_bf16(ak, aq[kk], sa[mi], 0, 0, 0);
        }
      // causal mask: s > q -> -inf
      if (s0 + 127 > qtb) {
        const int qg_ = qtb + w * 16 + lm;
#pragma unroll
        for (int mi = 0; mi < 8; ++mi)
#pragma unroll
          for (int r = 0; r < 4; ++r)
            if (s0 + mi * 16 + lq * 4 + r > qg_) sa[mi][r] = -3.0e38f;
      }
      // online softmax over s (in-lane 32 vals + 2 shfl levels)
      float mx = sa[0][0];
#pragma unroll
      for (int mi = 0; mi < 8; ++mi)
#pragma unroll
        for (int r = 0; r < 4; ++r) mx = fmaxf(mx, sa[mi][r]);
      mx = fmaxf(mx, __shfl_xor(mx, 16));
      mx = fmaxf(mx, __shfl_xor(mx, 32));
      const float mn = fmaxf(mq, mx);
      const float alpha = __expf(mq - mn);
      mq = mn;
      float sl = 0.0f;
#pragma unroll
      for (int mi = 0; mi < 8; ++mi)
#pragma unroll
        for (int r = 0; r < 4; ++r) {
          const float p = __expf(sa[mi][r] - mn);
          sa[mi][r] = p; sl += p;
        }
      sl += __shfl_xor(sl, 16);
      sl += __shfl_xor(sl, 32);
      lsum = lsum * alpha + sl;

      // P -> per-wave LDS [q][s], bf16, 4-short units, unit index (s/4) ^ lm
#pragma unroll
      for (int mi = 0; mi < 8; ++mi) {
        short4v pw;
#pragma unroll
        for (int r = 0; r < 4; ++r) pw[r] = (short)f2bf(sa[mi][r]);
        *(short4v*)&Ps[w * 2048 + lm * 128 + (((mi * 4 + lq)) ^ lm) * 4] = pw;
      }
      // rescale acc (alpha for q = lq*4+r lives in lane lq*4+r)
      float aP[4];
#pragma unroll
      for (int r = 0; r < 4; ++r) aP[r] = __shfl(alpha, lq * 4 + r);
#pragma unroll
      for (int hi = 0; hi < 8; ++hi) {
        f32x4 a = acc[hi];
#pragma unroll
        for (int r = 0; r < 4; ++r) a[r] *= aP[r];
        acc[hi] = a;
      }
      // O += P V : A = P[q][s] from Ps (k-block mi2 needs s/4 units
      // mi2*8 + lq*2 + {0,1}), B = V[s][h] from Vs (s/8 unit mi2*4 + lq)
#pragma unroll
      for (int mi2 = 0; mi2 < 4; ++mi2) {
        const short4v pa = *(const short4v*)&Ps[w * 2048 + lm * 128 + ((mi2 * 8 + lq * 2 + 0) ^ lm) * 4];
        const short4v pb = *(const short4v*)&Ps[w * 2048 + lm * 128 + ((mi2 * 8 + lq * 2 + 1) ^ lm) * 4];
        const short8 ap = __builtin_shufflevector(pa, pb, 0, 1, 2, 3, 4, 5, 6, 7);
#pragma unroll
        for (int hi = 0; hi < 8; ++hi) {
          const short8 bv = *(const short8*)&Vb[(hi * 16 + lm) * 128 + ((mi2 * 4 + lq) ^ lm) * 8];
          acc[hi] = __builtin_amdgcn_mfma_f32_16x16x32_bf16(ap, bv, acc[hi], 0, 0, 0);
        }
      }
    }
    // epilogue: 1/l, sigmoid gate, store (q = qtb + w*16 + lq*4 + r, h = hi*16+lm)
    const float linv = 1.0f / lsum;
    float lP[4];
#pragma unroll
    for (int r = 0; r < 4; ++r) lP[r] = __shfl(linv, lq * 4 + r);
#pragma unroll
    for (int hi = 0; hi < 8; ++hi)
#pragma unroll
      for (int r = 0; r < 4; ++r) {
        const int t = qtb + w * 16 + lq * 4 + r;
        const int h = hi * 16 + lm;
        const float g = bf2f(qgb[((size_t)t * NH_ + n) * 256 + 128 + h]);
        const float o = acc[hi][r] * lP[r] * (1.0f / (1.0f + __expf(-g)));
        encb[((size_t)t * NH_ + n) * 128 + h] = f2bf(o);
      }
  }
}

// ---------------------------------------------------------------------------
extern "C" void kernel_launch(void* const* d_in, const int* in_sizes, int n_in,
                              void* d_out, int out_size, void* d_ws, size_t ws_size,
                              hipStream_t stream)
{
  (void)in_sizes; (void)n_in; (void)out_size; (void)ws_size;
  const float* x0    = (const float*)d_in[0];
  const float* x1    = (const float*)d_in[1];
  const int*   pos   = (const int*)d_in[2];
  const float* qg_w0 = (const float*)d_in[4];
  const float* k_w0  = (const float*)d_in[5];
  const float* v_w0  = (const float*)d_in[6];
  const float* qn0   = (const float*)d_in[7];
  const float* kn0   = (const float*)d_in[8];
  const float* o_w0  = (const float*)d_in[9];
  const float* qg_w1 = (const float*)d_in[10];
  const float* k_w1  = (const float*)d_in[11];
  const float* v_w1  = (const float*)d_in[12];
  const float* qn1   = (const float*)d_in[13];
  const float* kn1   = (const float*)d_in[14];
  const float* o_w1  = (const float*)d_in[15];

  float* out    = (float*)d_out;
  float* kcache = out + (size_t)TT_ * WD_;
  float* vcache = kcache + (size_t)TT_ * KH_ * 128;
  ushort* qsc = (ushort*)d_out;  // out0/out1 region doubles as qg_w0^T scratch

  // ws: wbuf 16M | xb 8M (-> Kb 2M + Vt 2M after projections) | qgb 16M | encb 8M
  ushort* wbuf = (ushort*)d_ws;
  ushort* xb   = wbuf + 8388608;
  ushort* qgb  = xb + 4194304;
  ushort* encb = qgb + 8388608;
  ushort* Kbuf = xb;
  ushort* Vtb  = xb + 1048576;
  ushort* k0t = encb, *k1t = encb + 1048576, *v0t = encb + 2097152, *v1t = encb + 3145728;

  convert_x<<<4096, 256, 0, stream>>>(x0, x1, xb);

  // weight transposes
  convtrans2<<<dim3(64, 8, 32), 256, 0, stream>>>(qg_w0, qg_w1, qsc, wbuf, WD_, 256, 16);
  convtrans2<<<dim3(64, 4, 8), 256, 0, stream>>>(k_w0, k_w1, k0t, k1t, WD_, 128, 4);
  convtrans2<<<dim3(64, 4, 8), 256, 0, stream>>>(v_w0, v_w1, v0t, v1t, WD_, 128, 4);

  // all projections, one launch
  gemm_proj<<<dim3(40, 16), 256, 0, stream>>>(xb, qsc, wbuf, k0t, k1t, v0t, v1t,
                                              qgb, kcache, vcache);

  // norm + rope (kcache in place -> cached_k; Kb bf16 into xb alias)
  postproc<<<2048, 256, 0, stream>>>(qgb, kcache, Kbuf, pos, qn0, kn0, qn1, kn1);
  // Vt (kh*128+h, t) bf16 from vcache
  convtrans<<<dim3(64, 16, 1), 256, 0, stream>>>(vcache, Vtb, TT_, 512);

  attn<<<dim3(16, 16), 256, 0, stream>>>(qgb, Kbuf, Vtb, encb);

  // output projection
  convtrans2<<<dim3(64, 64, 2), 256, 0, stream>>>(o_w0, o_w1, wbuf, wbuf + 4194304, WD_, WD_, 1);
  gemm_out<<<dim3(16, 16), 256, 0, stream>>>(encb, wbuf, wbuf + 4194304, out);
}